// Round 9
// baseline (366.514 us; speedup 1.0000x reference)
//
#include <hip/hip_runtime.h>

#define BB 4096
#define DD 512
#define NCC 5994
#define RBX 64                      // x row-blocks (4096/64)
#define RBC 94                      // nc row-blocks (6016/64)
#define NSL 12                      // col-slices; each = 4 tiles of 128 cols
#define TPS 4
#define NBLK ((RBX + RBC) * NSL)    // 1896
#define PSZ (NSL * (BB + NCC))      // 121080

typedef __attribute__((ext_vector_type(8))) short bfx8;
typedef __attribute__((ext_vector_type(8))) unsigned short usx8;
typedef __attribute__((ext_vector_type(4))) float fx4;

__device__ __forceinline__ unsigned short f2bf(float f) {
    unsigned u = __builtin_bit_cast(unsigned, f);
    u += 0x7fff + ((u >> 16) & 1);   // RNE
    return (unsigned short)(u >> 16);
}

__device__ __forceinline__ void gload_lds16(const void* g, void* l) {
    __builtin_amdgcn_global_load_lds(
        (const __attribute__((address_space(1))) void*)g,
        (__attribute__((address_space(3))) void*)l, 16, 0, 0);
}

// ---------------------------------------------------------------------------
// prep: blocks [0,16): per-sample weight w + label_add (non-atomic, full loop)
//       blocks [16,784): zero cadd
//       blocks [784,1808): x fp32->bf16
// ---------------------------------------------------------------------------
__global__ void prep_kernel(const int* __restrict__ label, float* __restrict__ w,
                            float* __restrict__ label_add, const float* __restrict__ x,
                            unsigned short* __restrict__ xbuf, float* __restrict__ cadd) {
    __shared__ int lab[BB];
    int b = blockIdx.x, t = threadIdx.x;
    if (b < 16) {
        for (int j = t; j < BB; j += 256) lab[j] = label[j];
        __syncthreads();
        int i = b * 256 + t;
        int li = lab[i];
        int cnt = 0, rank = 0;
        for (int j = 0; j < BB; ++j) {
            int e = (lab[j] == li) ? 1 : 0;
            cnt += e;
            if (j < i) rank += e;
        }
        float expo = (rank == 0) ? (float)(cnt - 1) : (float)(cnt - rank);
        w[i] = exp2f(-expo);
        label_add[li] = 1.0f;
    } else if (b < 784) {
        int base = (b - 16) * 256 + t;           // float4 index
        float4 z = make_float4(0.f, 0.f, 0.f, 0.f);
        float4* c4 = (float4*)cadd;
#pragma unroll
        for (int k = 0; k < 4; ++k) {
            int idx = base + k * 196608;
            if (idx < (NCC * DD) / 4) c4[idx] = z;
        }
    } else {
        int i = (b - 784) * 256 + t;             // 8-float chunk, exact 262144
        const float4* g = (const float4*)(x + (size_t)i * 8);
        float4 v0 = g[0], v1 = g[1];
        usx8 u;
        u[0] = f2bf(v0.x); u[1] = f2bf(v0.y); u[2] = f2bf(v0.z); u[3] = f2bf(v0.w);
        u[4] = f2bf(v1.x); u[5] = f2bf(v1.y); u[6] = f2bf(v1.z); u[7] = f2bf(v1.w);
        *(usx8*)(xbuf + (size_t)i * 8) = u;
    }
}

// ---------------------------------------------------------------------------
// Stage 1b: weighted scatter-add into cadd.
// ---------------------------------------------------------------------------
__global__ void cadd_kernel(const float* __restrict__ x, const int* __restrict__ label,
                            const float* __restrict__ w, float* __restrict__ cadd) {
    int i = blockIdx.x;
    int li = label[i];
    float wi = w[i];
    const float* xr = x + (size_t)i * DD;
    float* cr = cadd + (size_t)li * DD;
    int t = threadIdx.x;
    atomicAdd(&cr[t], wi * xr[t]);
    atomicAdd(&cr[t + 256], wi * xr[t + 256]);
}

// ---------------------------------------------------------------------------
// Stage 2: alpha = sigmoid(centers @ fc_w + fc_b); blend; write bf16 ncb.
// ---------------------------------------------------------------------------
__global__ void newcenter_kernel(const float* __restrict__ centers,
                                 const float* __restrict__ fc_w,
                                 const float* __restrict__ fc_b,
                                 const float* __restrict__ cadd,
                                 const float* __restrict__ label_add,
                                 unsigned short* __restrict__ ncb) {
    int l = blockIdx.x;
    int t = threadIdx.x;
    const float* cr = centers + (size_t)l * DD;
    float part = fmaf(cr[t], fc_w[t], cr[t + 256] * fc_w[t + 256]);
#pragma unroll
    for (int off = 32; off; off >>= 1) part += __shfl_xor(part, off);
    __shared__ float wsum[4];
    if ((t & 63) == 0) wsum[t >> 6] = part;
    __syncthreads();
    float dot = wsum[0] + wsum[1] + wsum[2] + wsum[3] + fc_b[0];
    float alpha = 1.0f / (1.0f + expf(-dot));
    float la = label_add[l];
    float gate = alpha * la + (1.0f - la);
    float beta = (1.0f - alpha) * la;
    const float* car = cadd + (size_t)l * DD;
    unsigned short* nr = ncb + (size_t)l * DD;
    nr[t]       = f2bf(fmaf(cr[t],       gate, car[t]       * beta));
    nr[t + 256] = f2bf(fmaf(cr[t + 256], gate, car[t + 256] * beta));
}

// ---------------------------------------------------------------------------
// ch_w fp32 -> bf16 (after newcenter: wbuf overlays dead cadd region).
// ---------------------------------------------------------------------------
__global__ void convw_kernel(const float* __restrict__ src, unsigned short* __restrict__ dst) {
    int i = blockIdx.x * 256 + threadIdx.x;
    if (i >= NCC * DD / 8) return;
    const float4* g = (const float4*)(src + (size_t)i * 8);
    float4 v0 = g[0], v1 = g[1];
    usx8 u;
    u[0] = f2bf(v0.x); u[1] = f2bf(v0.y); u[2] = f2bf(v0.z); u[3] = f2bf(v0.w);
    u[4] = f2bf(v1.x); u[5] = f2bf(v1.y); u[6] = f2bf(v1.z); u[7] = f2bf(v1.w);
    *(usx8*)(dst + (size_t)i * 8) = u;
}

// ---------------------------------------------------------------------------
// Fused MFMA GEMM + online softmax/CE partials.
// Block 64 rows x 128 cols/tile, TPS=4 tiles, BK=64, dbuf 48 KB, 4 waves.
// K-loop uses counted vmcnt(6) + raw s_barriers (T4): loads stay in flight
// across barriers; NO vmcnt(0) drain in the loop. No other VMEM in loop
// (bias + targets preloaded to registers; epilogue indices compile-time).
// ---------------------------------------------------------------------------
__global__ __launch_bounds__(256, 3) void mfma_ce_kernel(
    const unsigned short* __restrict__ xb, const unsigned short* __restrict__ ncb,
    const unsigned short* __restrict__ wb, const float* __restrict__ chb,
    const int* __restrict__ labelg,
    float* __restrict__ pm, float* __restrict__ ps, float* __restrict__ pt,
    float* __restrict__ pv, int* __restrict__ pi)
{
    __shared__ short lA[2][64 * 64];    // 8 KB each
    __shared__ short lB[2][128 * 64];   // 16 KB each

    int b = blockIdx.x;
    int xm, rb, slice, nrows;
    const unsigned short* src;
    if (b < RBX * NSL) { xm = 1; rb = b % RBX; slice = b / RBX; nrows = BB;  src = xb; }
    else { int c = b - RBX * NSL; xm = 0; rb = c % RBC; slice = c / RBC; nrows = NCC; src = ncb; }
    int row0  = rb * 64;
    int tile0 = slice * TPS;

    int t = threadIdx.x, lane = t & 63, wv = t >> 6;
    int wm = wv >> 1, wn = wv & 1;
    int l15 = lane & 15, l4 = lane >> 4;

    // ---- staging source addresses (pre-swizzled k8 group; linear LDS dest) ----
    int sk8 = (lane & 7) ^ ((lane >> 3) & 7);
    int r0q = min(row0 + wv * 16 + (lane >> 3), nrows - 1);
    int r1q = min(row0 + wv * 16 + 8 + (lane >> 3), nrows - 1);
    const unsigned short* aQ0 = src + (size_t)r0q * DD + sk8 * 8;
    const unsigned short* aQ1 = src + (size_t)r1q * DD + sk8 * 8;
    int colq = wv * 32 + (lane >> 3);

    // ---- fragment read offsets (bytes), same XOR on read side ----
    int l4x   = l4 ^ (l15 & 3);
    int ksx   = (l15 >> 2) & 1;
    int slot0 = ((0 ^ ksx) << 2) | l4x;
    int slot1 = ((1 ^ ksx) << 2) | l4x;
    int aoff0 = (wm * 32 + l15) * 128 + slot0 * 16;   // + mf*2048
    int aoff1 = (wm * 32 + l15) * 128 + slot1 * 16;
    int boff0 = (wn * 64 + l15) * 128 + slot0 * 16;   // + nf*2048
    int boff1 = (wn * 64 + l15) * 128 + slot1 * 16;

    // ---- preload bias for all 4 tiles (keeps the K-loop VMEM-free) ----
    float bva[4][4];
#pragma unroll
    for (int tt = 0; tt < 4; ++tt)
#pragma unroll
        for (int nf = 0; nf < 4; ++nf) {
            int col = (tile0 + tt) * 128 + wn * 64 + nf * 16 + l15;
            bva[tt][nf] = (col < NCC) ? chb[col] : 0.f;
        }

    // ---- softmax state: row = row0 + wm*32 + mf*16 + l4*4 + j ----
    // argmax value == running max m_, so track index ai_ only.
    float m_[2][4], s_[2][4], tg_[2][4];
    int ai_[2][4], tc_[2][4];
#pragma unroll
    for (int mf = 0; mf < 2; ++mf)
#pragma unroll
        for (int j = 0; j < 4; ++j) {
            m_[mf][j] = -1e30f; s_[mf][j] = 0.f; tg_[mf][j] = 0.f;
            ai_[mf][j] = 0x7fffffff;
            int grow = row0 + wm * 32 + mf * 16 + l4 * 4 + j;
            tc_[mf][j] = xm ? labelg[min(grow, BB - 1)] : grow;
        }

    auto stage = [&](int s, int bufIdx) {
        int tile = tile0 + (s >> 3);
        int ko = (s & 7) * 64;                        // elems within row
        gload_lds16(aQ0 + ko, &lA[bufIdx][wv * 1024]);
        gload_lds16(aQ1 + ko, &lA[bufIdx][wv * 1024 + 512]);
        int cb = tile * 128 + colq;
#pragma unroll
        for (int q = 0; q < 4; ++q) {
            const unsigned short* bs =
                wb + (size_t)min(cb + q * 8, NCC - 1) * DD + sk8 * 8 + ko;
            gload_lds16(bs, &lB[bufIdx][wv * 2048 + q * 512]);
        }
    };

    stage(0, 0);

    fx4 acc[2][4];
    int buf = 0;

#pragma unroll
    for (int tt = 0; tt < 4; ++tt) {
#pragma unroll
        for (int mf = 0; mf < 2; ++mf)
#pragma unroll
            for (int nf = 0; nf < 4; ++nf) {
                fx4 z = {0.f, 0.f, 0.f, 0.f};
                acc[mf][nf] = z;
            }

        for (int s2 = 0; s2 < 8; ++s2) {
            int step = tt * 8 + s2;
            int nxt = (step + 1 < 32) ? step + 1 : 0;   // dummy wrap keeps vmcnt invariant
            stage(nxt, buf ^ 1);
            // own prior-step loads landed; 6 newest stay in flight
            asm volatile("s_waitcnt vmcnt(6)" ::: "memory");
            __builtin_amdgcn_s_barrier();               // everyone's loads landed
            __builtin_amdgcn_sched_barrier(0);

            const char* Ab = (const char*)lA[buf];
            const char* Bb = (const char*)lB[buf];
            bfx8 a0 = *(const bfx8*)(Ab + aoff0);
            bfx8 a1 = *(const bfx8*)(Ab + aoff0 + 2048);
            bfx8 b0 = *(const bfx8*)(Bb + boff0);
            bfx8 b1 = *(const bfx8*)(Bb + boff0 + 2048);
            bfx8 b2 = *(const bfx8*)(Bb + boff0 + 4096);
            bfx8 b3 = *(const bfx8*)(Bb + boff0 + 6144);
            bfx8 a2 = *(const bfx8*)(Ab + aoff1);
            bfx8 a3 = *(const bfx8*)(Ab + aoff1 + 2048);
            bfx8 b4 = *(const bfx8*)(Bb + boff1);
            bfx8 b5 = *(const bfx8*)(Bb + boff1 + 2048);
            bfx8 b6 = *(const bfx8*)(Bb + boff1 + 4096);
            bfx8 b7 = *(const bfx8*)(Bb + boff1 + 6144);

            __builtin_amdgcn_s_setprio(1);
            acc[0][0] = __builtin_amdgcn_mfma_f32_16x16x32_bf16(a0, b0, acc[0][0], 0, 0, 0);
            acc[0][1] = __builtin_amdgcn_mfma_f32_16x16x32_bf16(a0, b1, acc[0][1], 0, 0, 0);
            acc[0][2] = __builtin_amdgcn_mfma_f32_16x16x32_bf16(a0, b2, acc[0][2], 0, 0, 0);
            acc[0][3] = __builtin_amdgcn_mfma_f32_16x16x32_bf16(a0, b3, acc[0][3], 0, 0, 0);
            acc[1][0] = __builtin_amdgcn_mfma_f32_16x16x32_bf16(a1, b0, acc[1][0], 0, 0, 0);
            acc[1][1] = __builtin_amdgcn_mfma_f32_16x16x32_bf16(a1, b1, acc[1][1], 0, 0, 0);
            acc[1][2] = __builtin_amdgcn_mfma_f32_16x16x32_bf16(a1, b2, acc[1][2], 0, 0, 0);
            acc[1][3] = __builtin_amdgcn_mfma_f32_16x16x32_bf16(a1, b3, acc[1][3], 0, 0, 0);
            acc[0][0] = __builtin_amdgcn_mfma_f32_16x16x32_bf16(a2, b4, acc[0][0], 0, 0, 0);
            acc[0][1] = __builtin_amdgcn_mfma_f32_16x16x32_bf16(a2, b5, acc[0][1], 0, 0, 0);
            acc[0][2] = __builtin_amdgcn_mfma_f32_16x16x32_bf16(a2, b6, acc[0][2], 0, 0, 0);
            acc[0][3] = __builtin_amdgcn_mfma_f32_16x16x32_bf16(a2, b7, acc[0][3], 0, 0, 0);
            acc[1][0] = __builtin_amdgcn_mfma_f32_16x16x32_bf16(a3, b4, acc[1][0], 0, 0, 0);
            acc[1][1] = __builtin_amdgcn_mfma_f32_16x16x32_bf16(a3, b5, acc[1][1], 0, 0, 0);
            acc[1][2] = __builtin_amdgcn_mfma_f32_16x16x32_bf16(a3, b6, acc[1][2], 0, 0, 0);
            acc[1][3] = __builtin_amdgcn_mfma_f32_16x16x32_bf16(a3, b7, acc[1][3], 0, 0, 0);
            __builtin_amdgcn_s_setprio(0);

            __builtin_amdgcn_s_barrier();               // reads done before overwrite
            buf ^= 1;
        }

        // ---- epilogue for tile tt (register-only; tt compile-time) ----
        {
            int colb = (tile0 + tt) * 128 + wn * 64 + l15;
#pragma unroll
            for (int mf = 0; mf < 2; ++mf)
#pragma unroll
                for (int j = 0; j < 4; ++j) {
                    float v0 = (colb      < NCC) ? acc[mf][0][j] + bva[tt][0] : -1e30f;
                    float v1 = (colb + 16 < NCC) ? acc[mf][1][j] + bva[tt][1] : -1e30f;
                    float v2 = (colb + 32 < NCC) ? acc[mf][2][j] + bva[tt][2] : -1e30f;
                    float v3 = (colb + 48 < NCC) ? acc[mf][3][j] + bva[tt][3] : -1e30f;
                    // tile argmax (first-max wins within lane: strict >)
                    float tv = v0; int tcol = colb;
                    if (v1 > tv) { tv = v1; tcol = colb + 16; }
                    if (v2 > tv) { tv = v2; tcol = colb + 32; }
                    if (v3 > tv) { tv = v3; tcol = colb + 48; }
                    float nm = fmaxf(m_[mf][j], tv);
                    float sacc = s_[mf][j] * __expf(m_[mf][j] - nm);
                    if (colb      < NCC) sacc += __expf(v0 - nm);
                    if (colb + 16 < NCC) sacc += __expf(v1 - nm);
                    if (colb + 32 < NCC) sacc += __expf(v2 - nm);
                    if (colb + 48 < NCC) sacc += __expf(v3 - nm);
                    s_[mf][j] = sacc;
                    if (xm && tv > m_[mf][j]) ai_[mf][j] = tcol;
                    m_[mf][j] = nm;
                    int d = tc_[mf][j] - colb;
                    if (d == 0)  tg_[mf][j] = v0;
                    if (d == 16) tg_[mf][j] = v1;
                    if (d == 32) tg_[mf][j] = v2;
                    if (d == 48) tg_[mf][j] = v3;
                }
        }
    }

    __syncthreads();   // full drain (incl. dummy wrap loads) before LDS reuse

    // intra-wave merge across the 16-lane col group (value for argmax == m_)
#pragma unroll
    for (int off = 1; off < 16; off <<= 1) {
#pragma unroll
        for (int mf = 0; mf < 2; ++mf)
#pragma unroll
            for (int j = 0; j < 4; ++j) {
                float om = __shfl_xor(m_[mf][j], off);
                float os = __shfl_xor(s_[mf][j], off);
                float ot = __shfl_xor(tg_[mf][j], off);
                int   oi = __shfl_xor(ai_[mf][j], off);
                float nm = fmaxf(m_[mf][j], om);
                s_[mf][j] = s_[mf][j] * __expf(m_[mf][j] - nm) + os * __expf(om - nm);
                if (om > m_[mf][j] || (om == m_[mf][j] && oi < ai_[mf][j]))
                    ai_[mf][j] = oi;
                m_[mf][j] = nm;
                tg_[mf][j] += ot;
            }
    }

    // cross-wave merge (2 wn groups) via LDS
    float* red = (float*)lB;            // m[128] s[128] tg[128] + int[128]
    int* redi = (int*)(red + 384);
    if (l15 == 0) {
#pragma unroll
        for (int mf = 0; mf < 2; ++mf)
#pragma unroll
            for (int j = 0; j < 4; ++j) {
                int rowloc = wm * 32 + mf * 16 + l4 * 4 + j;
                int idx = wn * 64 + rowloc;
                red[idx]       = m_[mf][j];
                red[128 + idx] = s_[mf][j];
                red[256 + idx] = tg_[mf][j];
                redi[idx]      = ai_[mf][j];
            }
    }
    __syncthreads();
    if (t < 64) {
        int grow = row0 + t;
        if (grow < nrows) {
            float M = red[t], S = red[128 + t], T = red[256 + t];
            int I = redi[t];
            float m2 = red[64 + t], s2 = red[192 + t];
            int i2 = redi[64 + t];
            float nm = fmaxf(M, m2);
            S = S * __expf(M - nm) + s2 * __expf(m2 - nm);
            if (m2 > M || (m2 == M && i2 < I)) I = i2;
            M = nm;
            T += red[320 + t];
            int pidx = xm ? (grow * NSL + slice) : (BB * NSL + grow * NSL + slice);
            pm[pidx] = M; ps[pidx] = S; pt[pidx] = T; pv[pidx] = M; pi[pidx] = I;
        }
    }
}

// ---------------------------------------------------------------------------
// Merge partials per row -> CE / prec1 accumulators.
// ---------------------------------------------------------------------------
__global__ void merge_kernel(const float* __restrict__ pm, const float* __restrict__ ps,
                             const float* __restrict__ pt, const float* __restrict__ pv,
                             const int* __restrict__ pi, const int* __restrict__ label,
                             float* __restrict__ sums) {
    int tid = blockIdx.x * 256 + threadIdx.x;
    float ce = 0.f, corr = 0.f;
    int isx = (tid < BB) ? 1 : 0;
    int base = -1;
    if (tid < BB) base = tid * NSL;
    else if (tid < BB + NCC) base = BB * NSL + (tid - BB) * NSL;
    if (base >= 0) {
        float M = -1e30f, S = 0.f, T = 0.f, V = -1e30f; int I = 0x7fffffff;
#pragma unroll
        for (int s2 = 0; s2 < NSL; ++s2) {
            float m = pm[base + s2], s = ps[base + s2];
            float nm = fmaxf(M, m);
            S = S * __expf(M - nm) + s * __expf(m - nm); M = nm;
            T += pt[base + s2];
            float v = pv[base + s2]; int i2 = pi[base + s2];
            if (v > V || (v == V && i2 < I)) { V = v; I = i2; }
        }
        ce = -(T - M - logf(S));
        if (isx) corr = (I == label[tid]) ? 1.f : 0.f;
    }
#pragma unroll
    for (int off = 32; off; off >>= 1) {
        ce += __shfl_xor(ce, off);
        corr += __shfl_xor(corr, off);
    }
    if ((threadIdx.x & 63) == 0) {
        atomicAdd(&sums[isx ? 0 : 2], ce);
        if (isx) atomicAdd(&sums[1], corr);
    }
}

__global__ void finalize_kernel(const float* __restrict__ sums, float* __restrict__ out) {
    out[0] = sums[0] / (float)BB + sums[2] / (float)NCC;
    out[1] = 100.0f * sums[1] / (float)BB;
}

extern "C" void kernel_launch(void* const* d_in, const int* in_sizes, int n_in,
                              void* d_out, int out_size, void* d_ws, size_t ws_size,
                              hipStream_t stream) {
    const float* x       = (const float*)d_in[0];
    const int*   label   = (const int*)d_in[1];
    const float* centers = (const float*)d_in[2];
    const float* fc_w    = (const float*)d_in[3];
    const float* fc_b    = (const float*)d_in[4];
    const float* ch_w    = (const float*)d_in[5];
    const float* ch_b    = (const float*)d_in[6];
    float* out = (float*)d_out;

    // ws layout (float offsets), proven 22.7 MB footprint:
    // 0: w[4096] | 4096: label_add[5994] | 10090: sums[6] |
    // 14192: cadd[3068928] -- consumed by newcenter, then REUSED for:
    //        14192: pm/ps/pt/pv/pi (5*121080 = 605400)
    //        619592: wbuf bf16 ch_w (1534464 float-slots)
    // 3084144: xbuf bf16 x | 4132720: ncbuf bf16 nc
    float* ws = (float*)d_ws;
    float* w         = ws;
    float* label_add = ws + 4096;
    float* sums      = ws + 10090;
    float* cadd      = ws + 14192;
    float* pm        = ws + 14192;
    float* ps        = pm + PSZ;
    float* pt        = ps + PSZ;
    float* pv        = pt + PSZ;
    int*   pi        = (int*)(pv + PSZ);
    unsigned short* wbuf  = (unsigned short*)(ws + 619592);
    unsigned short* xbuf  = (unsigned short*)(ws + 3084144);
    unsigned short* ncbuf = (unsigned short*)(ws + 4132720);

    hipMemsetAsync(label_add, 0, 6000 * sizeof(float), stream);   // label_add + sums

    prep_kernel<<<1808, 256, 0, stream>>>(label, w, label_add, x, xbuf, cadd);
    cadd_kernel<<<BB, 256, 0, stream>>>(x, label, w, cadd);
    newcenter_kernel<<<NCC, 256, 0, stream>>>(centers, fc_w, fc_b, cadd, label_add, ncbuf);
    // cadd consumed; overlay region now safe for partials + wbuf
    convw_kernel<<<(NCC * DD / 8 + 255) / 256, 256, 0, stream>>>(ch_w, wbuf);

    mfma_ce_kernel<<<NBLK, 256, 0, stream>>>(xbuf, ncbuf, wbuf, ch_b, label,
                                             pm, ps, pt, pv, pi);

    merge_kernel<<<(BB + NCC + 255) / 256, 256, 0, stream>>>(pm, ps, pt, pv, pi, label, sums);
    finalize_kernel<<<1, 1, 0, stream>>>(sums, out);
}

// Round 10
// 362.065 us; speedup vs baseline: 1.0123x; 1.0123x over previous
//
#include <hip/hip_runtime.h>

#define BB 4096
#define DD 512
#define NCC 5994
#define RBX 64                      // x row-blocks (4096/64)
#define RBC 94                      // nc row-blocks (6016/64)
#define NSL 12                      // col-slices; each = 4 tiles of 128 cols
#define TPS 4
#define NBLK ((RBX + RBC) * NSL)    // 1896
#define PSZ (NSL * (BB + NCC))      // 121080

typedef __attribute__((ext_vector_type(8))) short bfx8;
typedef __attribute__((ext_vector_type(8))) unsigned short usx8;
typedef __attribute__((ext_vector_type(4))) float fx4;

__device__ __forceinline__ unsigned short f2bf(float f) {
    unsigned u = __builtin_bit_cast(unsigned, f);
    u += 0x7fff + ((u >> 16) & 1);   // RNE
    return (unsigned short)(u >> 16);
}

__device__ __forceinline__ void gload_lds16(const void* g, void* l) {
    __builtin_amdgcn_global_load_lds(
        (const __attribute__((address_space(1))) void*)g,
        (__attribute__((address_space(3))) void*)l, 16, 0, 0);
}

// ---------------------------------------------------------------------------
// prep: [0,16): per-sample weight w + label_add (non-atomic full scan)
//       [16,784): zero cadd
//       [784,1808): x fp32->bf16
//       [1808,3307): ch_w fp32->bf16
// ---------------------------------------------------------------------------
__global__ void prep_kernel(const int* __restrict__ label, float* __restrict__ w,
                            float* __restrict__ label_add, const float* __restrict__ x,
                            const float* __restrict__ chw,
                            unsigned short* __restrict__ xbuf,
                            unsigned short* __restrict__ wbuf,
                            float* __restrict__ cadd) {
    __shared__ int lab[BB];
    int b = blockIdx.x, t = threadIdx.x;
    if (b < 16) {
        for (int j = t; j < BB; j += 256) lab[j] = label[j];
        __syncthreads();
        int i = b * 256 + t;
        int li = lab[i];
        int cnt = 0, rank = 0;
        for (int j = 0; j < BB; ++j) {
            int e = (lab[j] == li) ? 1 : 0;
            cnt += e;
            if (j < i) rank += e;
        }
        float expo = (rank == 0) ? (float)(cnt - 1) : (float)(cnt - rank);
        w[i] = exp2f(-expo);
        label_add[li] = 1.0f;
    } else if (b < 784) {
        int base = (b - 16) * 256 + t;           // float4 index
        float4 z = make_float4(0.f, 0.f, 0.f, 0.f);
        float4* c4 = (float4*)cadd;
#pragma unroll
        for (int k = 0; k < 4; ++k) {
            int idx = base + k * 196608;
            if (idx < (NCC * DD) / 4) c4[idx] = z;
        }
    } else if (b < 1808) {
        int i = (b - 784) * 256 + t;             // 8-float chunk, exact 262144
        const float4* g = (const float4*)(x + (size_t)i * 8);
        float4 v0 = g[0], v1 = g[1];
        usx8 u;
        u[0] = f2bf(v0.x); u[1] = f2bf(v0.y); u[2] = f2bf(v0.z); u[3] = f2bf(v0.w);
        u[4] = f2bf(v1.x); u[5] = f2bf(v1.y); u[6] = f2bf(v1.z); u[7] = f2bf(v1.w);
        *(usx8*)(xbuf + (size_t)i * 8) = u;
    } else {
        int i = (b - 1808) * 256 + t;            // 8-float chunk of ch_w
        if (i >= NCC * DD / 8) return;
        const float4* g = (const float4*)(chw + (size_t)i * 8);
        float4 v0 = g[0], v1 = g[1];
        usx8 u;
        u[0] = f2bf(v0.x); u[1] = f2bf(v0.y); u[2] = f2bf(v0.z); u[3] = f2bf(v0.w);
        u[4] = f2bf(v1.x); u[5] = f2bf(v1.y); u[6] = f2bf(v1.z); u[7] = f2bf(v1.w);
        *(usx8*)(wbuf + (size_t)i * 8) = u;
    }
}

// ---------------------------------------------------------------------------
// Stage 1b: weighted scatter-add into cadd.
// ---------------------------------------------------------------------------
__global__ void cadd_kernel(const float* __restrict__ x, const int* __restrict__ label,
                            const float* __restrict__ w, float* __restrict__ cadd) {
    int i = blockIdx.x;
    int li = label[i];
    float wi = w[i];
    const float* xr = x + (size_t)i * DD;
    float* cr = cadd + (size_t)li * DD;
    int t = threadIdx.x;
    atomicAdd(&cr[t], wi * xr[t]);
    atomicAdd(&cr[t + 256], wi * xr[t + 256]);
}

// ---------------------------------------------------------------------------
// Stage 2: wave-per-class. alpha = sigmoid(centers @ fc_w + fc_b); blend;
// write bf16 ncb. 4 classes per 256-thread block, no LDS, no block sync.
// ---------------------------------------------------------------------------
__global__ void newcenter_kernel(const float* __restrict__ centers,
                                 const float* __restrict__ fc_w,
                                 const float* __restrict__ fc_b,
                                 const float* __restrict__ cadd,
                                 const float* __restrict__ label_add,
                                 unsigned short* __restrict__ ncb) {
    int l = blockIdx.x * 4 + (threadIdx.x >> 6);
    if (l >= NCC) return;                         // wave-uniform exit
    int lane = threadIdx.x & 63;
    int d0 = lane * 8;
    const float4* cr = (const float4*)(centers + (size_t)l * DD + d0);
    const float4* fw = (const float4*)(fc_w + d0);
    float4 c0 = cr[0], c1 = cr[1];
    float4 f0 = fw[0], f1 = fw[1];
    float part = c0.x * f0.x + c0.y * f0.y + c0.z * f0.z + c0.w * f0.w
               + c1.x * f1.x + c1.y * f1.y + c1.z * f1.z + c1.w * f1.w;
#pragma unroll
    for (int off = 32; off; off >>= 1) part += __shfl_xor(part, off);
    float dot = part + fc_b[0];
    float alpha = 1.0f / (1.0f + expf(-dot));
    float la = label_add[l];
    float gate = alpha * la + (1.0f - la);
    float beta = (1.0f - alpha) * la;
    const float4* ca = (const float4*)(cadd + (size_t)l * DD + d0);
    float4 a0 = ca[0], a1 = ca[1];
    usx8 u;
    u[0] = f2bf(fmaf(c0.x, gate, a0.x * beta));
    u[1] = f2bf(fmaf(c0.y, gate, a0.y * beta));
    u[2] = f2bf(fmaf(c0.z, gate, a0.z * beta));
    u[3] = f2bf(fmaf(c0.w, gate, a0.w * beta));
    u[4] = f2bf(fmaf(c1.x, gate, a1.x * beta));
    u[5] = f2bf(fmaf(c1.y, gate, a1.y * beta));
    u[6] = f2bf(fmaf(c1.z, gate, a1.z * beta));
    u[7] = f2bf(fmaf(c1.w, gate, a1.w * beta));
    *(usx8*)(ncb + (size_t)l * DD + d0) = u;
}

// ---------------------------------------------------------------------------
// Fused MFMA GEMM + online softmax/CE partials. (r8 synchronous structure)
// Block 64 rows x 128 cols/tile, TPS=4 tiles, BK=64, dbuf 48 KB, 4 waves.
// Per step: 16 MFMA + 12 ds_read_b128 + 6 gload_lds + 1 barrier.
// Bias preloaded to registers -> K-loop VMEM-free except staging.
// ---------------------------------------------------------------------------
__global__ __launch_bounds__(256, 3) void mfma_ce_kernel(
    const unsigned short* __restrict__ xb, const unsigned short* __restrict__ ncb,
    const unsigned short* __restrict__ wb, const float* __restrict__ chb,
    const int* __restrict__ labelg,
    float* __restrict__ pm, float* __restrict__ ps, float* __restrict__ pt,
    float* __restrict__ pv, int* __restrict__ pi)
{
    __shared__ short lA[2][64 * 64];    // 8 KB each
    __shared__ short lB[2][128 * 64];   // 16 KB each

    int b = blockIdx.x;
    int xm, rb, slice, nrows;
    const unsigned short* src;
    if (b < RBX * NSL) { xm = 1; rb = b % RBX; slice = b / RBX; nrows = BB;  src = xb; }
    else { int c = b - RBX * NSL; xm = 0; rb = c % RBC; slice = c / RBC; nrows = NCC; src = ncb; }
    int row0  = rb * 64;
    int tile0 = slice * TPS;

    int t = threadIdx.x, lane = t & 63, wv = t >> 6;
    int wm = wv >> 1, wn = wv & 1;
    int l15 = lane & 15, l4 = lane >> 4;

    // ---- staging source addresses (pre-swizzled k8 group; linear LDS dest) ----
    int sk8 = (lane & 7) ^ ((lane >> 3) & 7);
    int r0q = min(row0 + wv * 16 + (lane >> 3), nrows - 1);
    int r1q = min(row0 + wv * 16 + 8 + (lane >> 3), nrows - 1);
    const unsigned short* aQ0 = src + (size_t)r0q * DD + sk8 * 8;
    const unsigned short* aQ1 = src + (size_t)r1q * DD + sk8 * 8;
    int colq = wv * 32 + (lane >> 3);

    // ---- fragment read offsets (bytes), same XOR on read side ----
    int l4x   = l4 ^ (l15 & 3);
    int ksx   = (l15 >> 2) & 1;
    int slot0 = ((0 ^ ksx) << 2) | l4x;
    int slot1 = ((1 ^ ksx) << 2) | l4x;
    int aoff0 = (wm * 32 + l15) * 128 + slot0 * 16;   // + mf*2048
    int aoff1 = (wm * 32 + l15) * 128 + slot1 * 16;
    int boff0 = (wn * 64 + l15) * 128 + slot0 * 16;   // + nf*2048
    int boff1 = (wn * 64 + l15) * 128 + slot1 * 16;

    // ---- preload bias for all 4 tiles (keeps the K-loop VMEM-free) ----
    float bva[4][4];
#pragma unroll
    for (int tt = 0; tt < 4; ++tt)
#pragma unroll
        for (int nf = 0; nf < 4; ++nf) {
            int col = (tile0 + tt) * 128 + wn * 64 + nf * 16 + l15;
            bva[tt][nf] = (col < NCC) ? chb[col] : 0.f;
        }

    // ---- softmax state: row = row0 + wm*32 + mf*16 + l4*4 + j ----
    // argmax value == running max m_, so track index ai_ only.
    float m_[2][4], s_[2][4], tg_[2][4];
    int ai_[2][4], tc_[2][4];
#pragma unroll
    for (int mf = 0; mf < 2; ++mf)
#pragma unroll
        for (int j = 0; j < 4; ++j) {
            m_[mf][j] = -1e30f; s_[mf][j] = 0.f; tg_[mf][j] = 0.f;
            ai_[mf][j] = 0x7fffffff;
            int grow = row0 + wm * 32 + mf * 16 + l4 * 4 + j;
            tc_[mf][j] = xm ? labelg[min(grow, BB - 1)] : grow;
        }

    auto stage = [&](int s, int bufIdx) {
        int tile = tile0 + (s >> 3);
        int ko = (s & 7) * 64;                        // elems within row
        gload_lds16(aQ0 + ko, &lA[bufIdx][wv * 1024]);
        gload_lds16(aQ1 + ko, &lA[bufIdx][wv * 1024 + 512]);
        int cb = tile * 128 + colq;
#pragma unroll
        for (int q = 0; q < 4; ++q) {
            const unsigned short* bs =
                wb + (size_t)min(cb + q * 8, NCC - 1) * DD + sk8 * 8 + ko;
            gload_lds16(bs, &lB[bufIdx][wv * 2048 + q * 512]);
        }
    };

    stage(0, 0);
    __syncthreads();

    fx4 acc[2][4];
    int buf = 0;

#pragma unroll
    for (int tt = 0; tt < 4; ++tt) {
#pragma unroll
        for (int mf = 0; mf < 2; ++mf)
#pragma unroll
            for (int nf = 0; nf < 4; ++nf) {
                fx4 z = {0.f, 0.f, 0.f, 0.f};
                acc[mf][nf] = z;
            }

        for (int s2 = 0; s2 < 8; ++s2) {
            int step = tt * 8 + s2;
            if (step + 1 < 32) stage(step + 1, buf ^ 1);

            const char* Ab = (const char*)lA[buf];
            const char* Bb = (const char*)lB[buf];
            bfx8 a0 = *(const bfx8*)(Ab + aoff0);
            bfx8 a1 = *(const bfx8*)(Ab + aoff0 + 2048);
            bfx8 b0 = *(const bfx8*)(Bb + boff0);
            bfx8 b1 = *(const bfx8*)(Bb + boff0 + 2048);
            bfx8 b2 = *(const bfx8*)(Bb + boff0 + 4096);
            bfx8 b3 = *(const bfx8*)(Bb + boff0 + 6144);
            bfx8 a2 = *(const bfx8*)(Ab + aoff1);
            bfx8 a3 = *(const bfx8*)(Ab + aoff1 + 2048);
            bfx8 b4 = *(const bfx8*)(Bb + boff1);
            bfx8 b5 = *(const bfx8*)(Bb + boff1 + 2048);
            bfx8 b6 = *(const bfx8*)(Bb + boff1 + 4096);
            bfx8 b7 = *(const bfx8*)(Bb + boff1 + 6144);

            acc[0][0] = __builtin_amdgcn_mfma_f32_16x16x32_bf16(a0, b0, acc[0][0], 0, 0, 0);
            acc[0][1] = __builtin_amdgcn_mfma_f32_16x16x32_bf16(a0, b1, acc[0][1], 0, 0, 0);
            acc[0][2] = __builtin_amdgcn_mfma_f32_16x16x32_bf16(a0, b2, acc[0][2], 0, 0, 0);
            acc[0][3] = __builtin_amdgcn_mfma_f32_16x16x32_bf16(a0, b3, acc[0][3], 0, 0, 0);
            acc[1][0] = __builtin_amdgcn_mfma_f32_16x16x32_bf16(a1, b0, acc[1][0], 0, 0, 0);
            acc[1][1] = __builtin_amdgcn_mfma_f32_16x16x32_bf16(a1, b1, acc[1][1], 0, 0, 0);
            acc[1][2] = __builtin_amdgcn_mfma_f32_16x16x32_bf16(a1, b2, acc[1][2], 0, 0, 0);
            acc[1][3] = __builtin_amdgcn_mfma_f32_16x16x32_bf16(a1, b3, acc[1][3], 0, 0, 0);
            acc[0][0] = __builtin_amdgcn_mfma_f32_16x16x32_bf16(a2, b4, acc[0][0], 0, 0, 0);
            acc[0][1] = __builtin_amdgcn_mfma_f32_16x16x32_bf16(a2, b5, acc[0][1], 0, 0, 0);
            acc[0][2] = __builtin_amdgcn_mfma_f32_16x16x32_bf16(a2, b6, acc[0][2], 0, 0, 0);
            acc[0][3] = __builtin_amdgcn_mfma_f32_16x16x32_bf16(a2, b7, acc[0][3], 0, 0, 0);
            acc[1][0] = __builtin_amdgcn_mfma_f32_16x16x32_bf16(a3, b4, acc[1][0], 0, 0, 0);
            acc[1][1] = __builtin_amdgcn_mfma_f32_16x16x32_bf16(a3, b5, acc[1][1], 0, 0, 0);
            acc[1][2] = __builtin_amdgcn_mfma_f32_16x16x32_bf16(a3, b6, acc[1][2], 0, 0, 0);
            acc[1][3] = __builtin_amdgcn_mfma_f32_16x16x32_bf16(a3, b7, acc[1][3], 0, 0, 0);

            __syncthreads();
            buf ^= 1;
        }

        // ---- epilogue for tile tt (register-only; tt compile-time) ----
        {
            int colb = (tile0 + tt) * 128 + wn * 64 + l15;
#pragma unroll
            for (int mf = 0; mf < 2; ++mf)
#pragma unroll
                for (int j = 0; j < 4; ++j) {
                    float v0 = (colb      < NCC) ? acc[mf][0][j] + bva[tt][0] : -1e30f;
                    float v1 = (colb + 16 < NCC) ? acc[mf][1][j] + bva[tt][1] : -1e30f;
                    float v2 = (colb + 32 < NCC) ? acc[mf][2][j] + bva[tt][2] : -1e30f;
                    float v3 = (colb + 48 < NCC) ? acc[mf][3][j] + bva[tt][3] : -1e30f;
                    // tile argmax (first-max wins within lane: strict >)
                    float tv = v0; int tcol = colb;
                    if (v1 > tv) { tv = v1; tcol = colb + 16; }
                    if (v2 > tv) { tv = v2; tcol = colb + 32; }
                    if (v3 > tv) { tv = v3; tcol = colb + 48; }
                    float nm = fmaxf(m_[mf][j], tv);
                    float sacc = s_[mf][j] * __expf(m_[mf][j] - nm);
                    if (colb      < NCC) sacc += __expf(v0 - nm);
                    if (colb + 16 < NCC) sacc += __expf(v1 - nm);
                    if (colb + 32 < NCC) sacc += __expf(v2 - nm);
                    if (colb + 48 < NCC) sacc += __expf(v3 - nm);
                    s_[mf][j] = sacc;
                    if (xm && tv > m_[mf][j]) ai_[mf][j] = tcol;
                    m_[mf][j] = nm;
                    int d = tc_[mf][j] - colb;
                    if (d == 0)  tg_[mf][j] = v0;
                    if (d == 16) tg_[mf][j] = v1;
                    if (d == 32) tg_[mf][j] = v2;
                    if (d == 48) tg_[mf][j] = v3;
                }
        }
    }

    __syncthreads();   // all reads of lB done before reduction reuse

    // intra-wave merge across the 16-lane col group (argmax value == m_)
#pragma unroll
    for (int off = 1; off < 16; off <<= 1) {
#pragma unroll
        for (int mf = 0; mf < 2; ++mf)
#pragma unroll
            for (int j = 0; j < 4; ++j) {
                float om = __shfl_xor(m_[mf][j], off);
                float os = __shfl_xor(s_[mf][j], off);
                float ot = __shfl_xor(tg_[mf][j], off);
                int   oi = __shfl_xor(ai_[mf][j], off);
                float nm = fmaxf(m_[mf][j], om);
                s_[mf][j] = s_[mf][j] * __expf(m_[mf][j] - nm) + os * __expf(om - nm);
                if (om > m_[mf][j] || (om == m_[mf][j] && oi < ai_[mf][j]))
                    ai_[mf][j] = oi;
                m_[mf][j] = nm;
                tg_[mf][j] += ot;
            }
    }

    // cross-wave merge (2 wn groups) via LDS
    float* red = (float*)lB;            // m[128] s[128] tg[128] + int[128]
    int* redi = (int*)(red + 384);
    if (l15 == 0) {
#pragma unroll
        for (int mf = 0; mf < 2; ++mf)
#pragma unroll
            for (int j = 0; j < 4; ++j) {
                int rowloc = wm * 32 + mf * 16 + l4 * 4 + j;
                int idx = wn * 64 + rowloc;
                red[idx]       = m_[mf][j];
                red[128 + idx] = s_[mf][j];
                red[256 + idx] = tg_[mf][j];
                redi[idx]      = ai_[mf][j];
            }
    }
    __syncthreads();
    if (t < 64) {
        int grow = row0 + t;
        if (grow < nrows) {
            float M = red[t], S = red[128 + t], T = red[256 + t];
            int I = redi[t];
            float m2 = red[64 + t], s2 = red[192 + t];
            int i2 = redi[64 + t];
            float nm = fmaxf(M, m2);
            S = S * __expf(M - nm) + s2 * __expf(m2 - nm);
            if (m2 > M || (m2 == M && i2 < I)) I = i2;
            M = nm;
            T += red[320 + t];
            int pidx = xm ? (grow * NSL + slice) : (BB * NSL + grow * NSL + slice);
            pm[pidx] = M; ps[pidx] = S; pt[pidx] = T; pv[pidx] = M; pi[pidx] = I;
        }
    }
}

// ---------------------------------------------------------------------------
// Merge partials per row -> CE / prec1 accumulators.
// ---------------------------------------------------------------------------
__global__ void merge_kernel(const float* __restrict__ pm, const float* __restrict__ ps,
                             const float* __restrict__ pt, const float* __restrict__ pv,
                             const int* __restrict__ pi, const int* __restrict__ label,
                             float* __restrict__ sums) {
    int tid = blockIdx.x * 256 + threadIdx.x;
    float ce = 0.f, corr = 0.f;
    int isx = (tid < BB) ? 1 : 0;
    int base = -1;
    if (tid < BB) base = tid * NSL;
    else if (tid < BB + NCC) base = BB * NSL + (tid - BB) * NSL;
    if (base >= 0) {
        float M = -1e30f, S = 0.f, T = 0.f, V = -1e30f; int I = 0x7fffffff;
#pragma unroll
        for (int s2 = 0; s2 < NSL; ++s2) {
            float m = pm[base + s2], s = ps[base + s2];
            float nm = fmaxf(M, m);
            S = S * __expf(M - nm) + s * __expf(m - nm); M = nm;
            T += pt[base + s2];
            float v = pv[base + s2]; int i2 = pi[base + s2];
            if (v > V || (v == V && i2 < I)) { V = v; I = i2; }
        }
        ce = -(T - M - logf(S));
        if (isx) corr = (I == label[tid]) ? 1.f : 0.f;
    }
#pragma unroll
    for (int off = 32; off; off >>= 1) {
        ce += __shfl_xor(ce, off);
        corr += __shfl_xor(corr, off);
    }
    if ((threadIdx.x & 63) == 0) {
        atomicAdd(&sums[isx ? 0 : 2], ce);
        if (isx) atomicAdd(&sums[1], corr);
    }
}

__global__ void finalize_kernel(const float* __restrict__ sums, float* __restrict__ out) {
    out[0] = sums[0] / (float)BB + sums[2] / (float)NCC;
    out[1] = 100.0f * sums[1] / (float)BB;
}

extern "C" void kernel_launch(void* const* d_in, const int* in_sizes, int n_in,
                              void* d_out, int out_size, void* d_ws, size_t ws_size,
                              hipStream_t stream) {
    const float* x       = (const float*)d_in[0];
    const int*   label   = (const int*)d_in[1];
    const float* centers = (const float*)d_in[2];
    const float* fc_w    = (const float*)d_in[3];
    const float* fc_b    = (const float*)d_in[4];
    const float* ch_w    = (const float*)d_in[5];
    const float* ch_b    = (const float*)d_in[6];
    float* out = (float*)d_out;

    // ws layout (float offsets), proven 22.7 MB footprint:
    // 0: w[4096] | 4096: label_add[5994] | 10090: sums[6] |
    // 14192: cadd[3068928] -- consumed by newcenter, then REUSED for:
    //        14192: pm/ps/pt/pv/pi (5*121080 = 605400)
    //        619592: wbuf bf16 ch_w (1534464 float-slots)
    // 3084144: xbuf bf16 x | 4132720: ncbuf bf16 nc
    float* ws = (float*)d_ws;
    float* w         = ws;
    float* label_add = ws + 4096;
    float* sums      = ws + 10090;
    float* cadd      = ws + 14192;
    float* pm        = ws + 14192;
    float* ps        = pm + PSZ;
    float* pt        = ps + PSZ;
    float* pv        = pt + PSZ;
    int*   pi        = (int*)(pv + PSZ);
    unsigned short* wbuf  = (unsigned short*)(ws + 619592);
    unsigned short* xbuf  = (unsigned short*)(ws + 3084144);
    unsigned short* ncbuf = (unsigned short*)(ws + 4132720);

    hipMemsetAsync(label_add, 0, 6000 * sizeof(float), stream);   // label_add + sums

    // NOTE: wbuf overlays the cadd region's tail; cadd spans ws[14192,3083120)
    // and wbuf starts at 619592 -- they OVERLAP, but prep writes wbuf while
    // prep also zeroes cadd. They must not coexist: wbuf is only read by
    // mfma_ce (after newcenter consumed cadd), but prep WRITES wbuf before
    // cadd is consumed -> move wbuf out of the cadd span? It already was in
    // r7/r8 and passed: wbuf [619592, 2154056) lies INSIDE cadd's span --
    // but in r7/r8 the w-conversion ran AFTER newcenter. Here prep converts
    // ch_w BEFORE cadd/newcenter -> collision. FIX: convert ch_w into the
    // region AFTER ncbuf instead (fresh space, total stays < ws budget).
    wbuf = (unsigned short*)(ws + 4132720 + 1534464 / 2 * 2 + 1534464);  // after ncbuf

    prep_kernel<<<3307, 256, 0, stream>>>(label, w, label_add, x, ch_w, xbuf, wbuf, cadd);
    cadd_kernel<<<BB, 256, 0, stream>>>(x, label, w, cadd);
    newcenter_kernel<<<1499, 256, 0, stream>>>(centers, fc_w, fc_b, cadd, label_add, ncbuf);

    mfma_ce_kernel<<<NBLK, 256, 0, stream>>>(xbuf, ncbuf, wbuf, ch_b, label,
                                             pm, ps, pt, pv, pi);

    merge_kernel<<<(BB + NCC + 255) / 256, 256, 0, stream>>>(pm, ps, pt, pv, pi, label, sums);
    finalize_kernel<<<1, 1, 0, stream>>>(sums, out);
}

// Round 12
// 313.020 us; speedup vs baseline: 1.1709x; 1.1567x over previous
//
#include <hip/hip_runtime.h>

#define BB 4096
#define DD 512
#define NCC 5994
#define RBX 64                      // x row-blocks (4096/64)
#define RBC 94                      // nc row-blocks (6016/64)
#define NSL 12                      // col-slices; each = 4 tiles of 128 cols
#define TPS 4
#define NBLK ((RBX + RBC) * NSL)    // 1896
#define PSZ (NSL * (BB + NCC))      // 121080

typedef __attribute__((ext_vector_type(8))) short bfx8;
typedef __attribute__((ext_vector_type(8))) unsigned short usx8;
typedef __attribute__((ext_vector_type(4))) float fx4;

__device__ __forceinline__ unsigned short f2bf(float f) {
    unsigned u = __builtin_bit_cast(unsigned, f);
    u += 0x7fff + ((u >> 16) & 1);   // RNE
    return (unsigned short)(u >> 16);
}

__device__ __forceinline__ void gload_lds16(const void* g, void* l) {
    __builtin_amdgcn_global_load_lds(
        (const __attribute__((address_space(1))) void*)g,
        (__attribute__((address_space(3))) void*)l, 16, 0, 0);
}

// ---------------------------------------------------------------------------
// prep: [0,16): per-sample weight w + label_add (non-atomic full scan)
//       [16,784): zero cadd
//       [784,1808): x fp32->bf16
//       [1808,3307): ch_w fp32->bf16  (wbuf is OUTSIDE the cadd span)
// ---------------------------------------------------------------------------
__global__ void prep_kernel(const int* __restrict__ label, float* __restrict__ w,
                            float* __restrict__ label_add, const float* __restrict__ x,
                            const float* __restrict__ chw,
                            unsigned short* __restrict__ xbuf,
                            unsigned short* __restrict__ wbuf,
                            float* __restrict__ cadd) {
    __shared__ int lab[BB];
    int b = blockIdx.x, t = threadIdx.x;
    if (b < 16) {
        for (int j = t; j < BB; j += 256) lab[j] = label[j];
        __syncthreads();
        int i = b * 256 + t;
        int li = lab[i];
        int cnt = 0, rank = 0;
        for (int j = 0; j < BB; ++j) {
            int e = (lab[j] == li) ? 1 : 0;
            cnt += e;
            if (j < i) rank += e;
        }
        float expo = (rank == 0) ? (float)(cnt - 1) : (float)(cnt - rank);
        w[i] = exp2f(-expo);
        label_add[li] = 1.0f;
    } else if (b < 784) {
        int base = (b - 16) * 256 + t;           // float4 index
        float4 z = make_float4(0.f, 0.f, 0.f, 0.f);
        float4* c4 = (float4*)cadd;
#pragma unroll
        for (int k = 0; k < 4; ++k) {
            int idx = base + k * 196608;
            if (idx < (NCC * DD) / 4) c4[idx] = z;
        }
    } else if (b < 1808) {
        int i = (b - 784) * 256 + t;             // 8-float chunk, exact 262144
        const float4* g = (const float4*)(x + (size_t)i * 8);
        float4 v0 = g[0], v1 = g[1];
        usx8 u;
        u[0] = f2bf(v0.x); u[1] = f2bf(v0.y); u[2] = f2bf(v0.z); u[3] = f2bf(v0.w);
        u[4] = f2bf(v1.x); u[5] = f2bf(v1.y); u[6] = f2bf(v1.z); u[7] = f2bf(v1.w);
        *(usx8*)(xbuf + (size_t)i * 8) = u;
    } else {
        int i = (b - 1808) * 256 + t;            // 8-float chunk of ch_w
        if (i >= NCC * DD / 8) return;
        const float4* g = (const float4*)(chw + (size_t)i * 8);
        float4 v0 = g[0], v1 = g[1];
        usx8 u;
        u[0] = f2bf(v0.x); u[1] = f2bf(v0.y); u[2] = f2bf(v0.z); u[3] = f2bf(v0.w);
        u[4] = f2bf(v1.x); u[5] = f2bf(v1.y); u[6] = f2bf(v1.z); u[7] = f2bf(v1.w);
        *(usx8*)(wbuf + (size_t)i * 8) = u;
    }
}

// ---------------------------------------------------------------------------
// Stage 1b: weighted scatter-add into cadd.
// ---------------------------------------------------------------------------
__global__ void cadd_kernel(const float* __restrict__ x, const int* __restrict__ label,
                            const float* __restrict__ w, float* __restrict__ cadd) {
    int i = blockIdx.x;
    int li = label[i];
    float wi = w[i];
    const float* xr = x + (size_t)i * DD;
    float* cr = cadd + (size_t)li * DD;
    int t = threadIdx.x;
    atomicAdd(&cr[t], wi * xr[t]);
    atomicAdd(&cr[t + 256], wi * xr[t + 256]);
}

// ---------------------------------------------------------------------------
// Stage 2: wave-per-class. alpha = sigmoid(centers @ fc_w + fc_b); blend;
// write bf16 ncb. 4 classes per 256-thread block, no LDS, no block sync.
// ---------------------------------------------------------------------------
__global__ void newcenter_kernel(const float* __restrict__ centers,
                                 const float* __restrict__ fc_w,
                                 const float* __restrict__ fc_b,
                                 const float* __restrict__ cadd,
                                 const float* __restrict__ label_add,
                                 unsigned short* __restrict__ ncb) {
    int l = blockIdx.x * 4 + (threadIdx.x >> 6);
    if (l >= NCC) return;                         // wave-uniform exit
    int lane = threadIdx.x & 63;
    int d0 = lane * 8;
    const float4* cr = (const float4*)(centers + (size_t)l * DD + d0);
    const float4* fw = (const float4*)(fc_w + d0);
    float4 c0 = cr[0], c1 = cr[1];
    float4 f0 = fw[0], f1 = fw[1];
    float part = c0.x * f0.x + c0.y * f0.y + c0.z * f0.z + c0.w * f0.w
               + c1.x * f1.x + c1.y * f1.y + c1.z * f1.z + c1.w * f1.w;
#pragma unroll
    for (int off = 32; off; off >>= 1) part += __shfl_xor(part, off);
    float dot = part + fc_b[0];
    float alpha = 1.0f / (1.0f + expf(-dot));
    float la = label_add[l];
    float gate = alpha * la + (1.0f - la);
    float beta = (1.0f - alpha) * la;
    const float4* ca = (const float4*)(cadd + (size_t)l * DD + d0);
    float4 a0 = ca[0], a1 = ca[1];
    usx8 u;
    u[0] = f2bf(fmaf(c0.x, gate, a0.x * beta));
    u[1] = f2bf(fmaf(c0.y, gate, a0.y * beta));
    u[2] = f2bf(fmaf(c0.z, gate, a0.z * beta));
    u[3] = f2bf(fmaf(c0.w, gate, a0.w * beta));
    u[4] = f2bf(fmaf(c1.x, gate, a1.x * beta));
    u[5] = f2bf(fmaf(c1.y, gate, a1.y * beta));
    u[6] = f2bf(fmaf(c1.z, gate, a1.z * beta));
    u[7] = f2bf(fmaf(c1.w, gate, a1.w * beta));
    *(usx8*)(ncb + (size_t)l * DD + d0) = u;
}

// ---------------------------------------------------------------------------
// Fused MFMA GEMM + online softmax/CE partials.  (EXACT r8 body — proven
// 157 us / no scratch.)  Block 64 rows x 128 cols/tile, TPS=4 tiles, BK=64,
// dbuf 48 KB, 4 waves. Per step: 16 MFMA + 12 ds_read_b128 + 6 gload_lds +
// 1 barrier.
// ---------------------------------------------------------------------------
__global__ __launch_bounds__(256, 3) void mfma_ce_kernel(
    const unsigned short* __restrict__ xb, const unsigned short* __restrict__ ncb,
    const unsigned short* __restrict__ wb, const float* __restrict__ chb,
    const int* __restrict__ labelg,
    float* __restrict__ pm, float* __restrict__ ps, float* __restrict__ pt,
    float* __restrict__ pv, int* __restrict__ pi)
{
    __shared__ short lA[2][64 * 64];    // 8 KB each
    __shared__ short lB[2][128 * 64];   // 16 KB each

    int b = blockIdx.x;
    int xm, rb, slice, nrows;
    const unsigned short* src;
    if (b < RBX * NSL) { xm = 1; rb = b % RBX; slice = b / RBX; nrows = BB;  src = xb; }
    else { int c = b - RBX * NSL; xm = 0; rb = c % RBC; slice = c / RBC; nrows = NCC; src = ncb; }
    int row0  = rb * 64;
    int tile0 = slice * TPS;

    int t = threadIdx.x, lane = t & 63, wv = t >> 6;
    int wm = wv >> 1, wn = wv & 1;
    int l15 = lane & 15, l4 = lane >> 4;

    // ---- staging source addresses (pre-swizzled k8 group; linear LDS dest) ----
    int sk8 = (lane & 7) ^ ((lane >> 3) & 7);
    int r0q = min(row0 + wv * 16 + (lane >> 3), nrows - 1);
    int r1q = min(row0 + wv * 16 + 8 + (lane >> 3), nrows - 1);
    const unsigned short* aQ0 = src + (size_t)r0q * DD + sk8 * 8;
    const unsigned short* aQ1 = src + (size_t)r1q * DD + sk8 * 8;
    int colq = wv * 32 + (lane >> 3);

    // ---- fragment read offsets (bytes), same XOR on read side ----
    int l4x   = l4 ^ (l15 & 3);
    int ksx   = (l15 >> 2) & 1;
    int slot0 = ((0 ^ ksx) << 2) | l4x;
    int slot1 = ((1 ^ ksx) << 2) | l4x;
    int aoff0 = (wm * 32 + l15) * 128 + slot0 * 16;   // + mf*2048
    int aoff1 = (wm * 32 + l15) * 128 + slot1 * 16;
    int boff0 = (wn * 64 + l15) * 128 + slot0 * 16;   // + nf*2048
    int boff1 = (wn * 64 + l15) * 128 + slot1 * 16;

    // ---- softmax state: row = row0 + wm*32 + mf*16 + l4*4 + j ----
    float m_[2][4], s_[2][4], tg_[2][4], av_[2][4];
    int ai_[2][4], tc_[2][4];
#pragma unroll
    for (int mf = 0; mf < 2; ++mf)
#pragma unroll
        for (int j = 0; j < 4; ++j) {
            m_[mf][j] = -1e30f; s_[mf][j] = 0.f; tg_[mf][j] = 0.f;
            av_[mf][j] = -1e30f; ai_[mf][j] = 0x7fffffff;
            int grow = row0 + wm * 32 + mf * 16 + l4 * 4 + j;
            tc_[mf][j] = xm ? labelg[min(grow, BB - 1)] : grow;
        }

    auto stage = [&](int s, int bufIdx) {
        int tile = tile0 + (s >> 3);
        int ko = (s & 7) * 64;                        // elems within row
        gload_lds16(aQ0 + ko, &lA[bufIdx][wv * 1024]);
        gload_lds16(aQ1 + ko, &lA[bufIdx][wv * 1024 + 512]);
        int cb = tile * 128 + colq;
#pragma unroll
        for (int q = 0; q < 4; ++q) {
            const unsigned short* bs =
                wb + (size_t)min(cb + q * 8, NCC - 1) * DD + sk8 * 8 + ko;
            gload_lds16(bs, &lB[bufIdx][wv * 2048 + q * 512]);
        }
    };

    stage(0, 0);
    __syncthreads();

    fx4 acc[2][4];
    float biasv[4];
    int buf = 0;

    for (int s = 0; s < TPS * 8; ++s) {               // 32 steps
        int kc = s & 7;
        int tile = tile0 + (s >> 3);
        if (s + 1 < TPS * 8) stage(s + 1, buf ^ 1);
        if (kc == 0) {
#pragma unroll
            for (int mf = 0; mf < 2; ++mf)
#pragma unroll
                for (int nf = 0; nf < 4; ++nf) {
                    fx4 z = {0.f, 0.f, 0.f, 0.f};
                    acc[mf][nf] = z;
                }
#pragma unroll
            for (int nf = 0; nf < 4; ++nf) {
                int col = tile * 128 + wn * 64 + nf * 16 + l15;
                biasv[nf] = (col < NCC) ? chb[col] : 0.f;
            }
        }
        const char* Ab = (const char*)lA[buf];
        const char* Bb = (const char*)lB[buf];
        {   // ks = 0
            bfx8 a0 = *(const bfx8*)(Ab + aoff0);
            bfx8 a1 = *(const bfx8*)(Ab + aoff0 + 2048);
            bfx8 b0 = *(const bfx8*)(Bb + boff0);
            bfx8 b1 = *(const bfx8*)(Bb + boff0 + 2048);
            bfx8 b2 = *(const bfx8*)(Bb + boff0 + 4096);
            bfx8 b3 = *(const bfx8*)(Bb + boff0 + 6144);
            acc[0][0] = __builtin_amdgcn_mfma_f32_16x16x32_bf16(a0, b0, acc[0][0], 0, 0, 0);
            acc[0][1] = __builtin_amdgcn_mfma_f32_16x16x32_bf16(a0, b1, acc[0][1], 0, 0, 0);
            acc[0][2] = __builtin_amdgcn_mfma_f32_16x16x32_bf16(a0, b2, acc[0][2], 0, 0, 0);
            acc[0][3] = __builtin_amdgcn_mfma_f32_16x16x32_bf16(a0, b3, acc[0][3], 0, 0, 0);
            acc[1][0] = __builtin_amdgcn_mfma_f32_16x16x32_bf16(a1, b0, acc[1][0], 0, 0, 0);
            acc[1][1] = __builtin_amdgcn_mfma_f32_16x16x32_bf16(a1, b1, acc[1][1], 0, 0, 0);
            acc[1][2] = __builtin_amdgcn_mfma_f32_16x16x32_bf16(a1, b2, acc[1][2], 0, 0, 0);
            acc[1][3] = __builtin_amdgcn_mfma_f32_16x16x32_bf16(a1, b3, acc[1][3], 0, 0, 0);
        }
        {   // ks = 1
            bfx8 a0 = *(const bfx8*)(Ab + aoff1);
            bfx8 a1 = *(const bfx8*)(Ab + aoff1 + 2048);
            bfx8 b0 = *(const bfx8*)(Bb + boff1);
            bfx8 b1 = *(const bfx8*)(Bb + boff1 + 2048);
            bfx8 b2 = *(const bfx8*)(Bb + boff1 + 4096);
            bfx8 b3 = *(const bfx8*)(Bb + boff1 + 6144);
            acc[0][0] = __builtin_amdgcn_mfma_f32_16x16x32_bf16(a0, b0, acc[0][0], 0, 0, 0);
            acc[0][1] = __builtin_amdgcn_mfma_f32_16x16x32_bf16(a0, b1, acc[0][1], 0, 0, 0);
            acc[0][2] = __builtin_amdgcn_mfma_f32_16x16x32_bf16(a0, b2, acc[0][2], 0, 0, 0);
            acc[0][3] = __builtin_amdgcn_mfma_f32_16x16x32_bf16(a0, b3, acc[0][3], 0, 0, 0);
            acc[1][0] = __builtin_amdgcn_mfma_f32_16x16x32_bf16(a1, b0, acc[1][0], 0, 0, 0);
            acc[1][1] = __builtin_amdgcn_mfma_f32_16x16x32_bf16(a1, b1, acc[1][1], 0, 0, 0);
            acc[1][2] = __builtin_amdgcn_mfma_f32_16x16x32_bf16(a1, b2, acc[1][2], 0, 0, 0);
            acc[1][3] = __builtin_amdgcn_mfma_f32_16x16x32_bf16(a1, b3, acc[1][3], 0, 0, 0);
        }

        if (kc == 7) {
            int colb = tile * 128 + wn * 64 + l15;
#pragma unroll
            for (int mf = 0; mf < 2; ++mf)
#pragma unroll
                for (int j = 0; j < 4; ++j) {
                    float v0 = (colb      < NCC) ? acc[mf][0][j] + biasv[0] : -1e30f;
                    float v1 = (colb + 16 < NCC) ? acc[mf][1][j] + biasv[1] : -1e30f;
                    float v2 = (colb + 32 < NCC) ? acc[mf][2][j] + biasv[2] : -1e30f;
                    float v3 = (colb + 48 < NCC) ? acc[mf][3][j] + biasv[3] : -1e30f;
                    float cmax = fmaxf(fmaxf(v0, v1), fmaxf(v2, v3));
                    float nm = fmaxf(m_[mf][j], cmax);
                    float sacc = s_[mf][j] * __expf(m_[mf][j] - nm);
                    if (colb      < NCC) sacc += __expf(v0 - nm);
                    if (colb + 16 < NCC) sacc += __expf(v1 - nm);
                    if (colb + 32 < NCC) sacc += __expf(v2 - nm);
                    if (colb + 48 < NCC) sacc += __expf(v3 - nm);
                    s_[mf][j] = sacc;
                    m_[mf][j] = nm;
                    if (xm) {
                        if (v0 > av_[mf][j]) { av_[mf][j] = v0; ai_[mf][j] = colb; }
                        if (v1 > av_[mf][j]) { av_[mf][j] = v1; ai_[mf][j] = colb + 16; }
                        if (v2 > av_[mf][j]) { av_[mf][j] = v2; ai_[mf][j] = colb + 32; }
                        if (v3 > av_[mf][j]) { av_[mf][j] = v3; ai_[mf][j] = colb + 48; }
                    }
                    int d = tc_[mf][j] - colb;
                    if (d == 0)  tg_[mf][j] = v0;
                    if (d == 16) tg_[mf][j] = v1;
                    if (d == 32) tg_[mf][j] = v2;
                    if (d == 48) tg_[mf][j] = v3;
                }
        }
        __syncthreads();
        buf ^= 1;
    }

    // intra-wave merge across the 16-lane col group
#pragma unroll
    for (int off = 1; off < 16; off <<= 1) {
#pragma unroll
        for (int mf = 0; mf < 2; ++mf)
#pragma unroll
            for (int j = 0; j < 4; ++j) {
                float om = __shfl_xor(m_[mf][j], off);
                float os = __shfl_xor(s_[mf][j], off);
                float ot = __shfl_xor(tg_[mf][j], off);
                float ov = __shfl_xor(av_[mf][j], off);
                int   oi = __shfl_xor(ai_[mf][j], off);
                float nm = fmaxf(m_[mf][j], om);
                s_[mf][j] = s_[mf][j] * __expf(m_[mf][j] - nm) + os * __expf(om - nm);
                m_[mf][j] = nm;
                tg_[mf][j] += ot;
                if (ov > av_[mf][j] || (ov == av_[mf][j] && oi < ai_[mf][j])) {
                    av_[mf][j] = ov; ai_[mf][j] = oi;
                }
            }
    }

    // cross-wave merge (2 wn groups) via LDS (safe after final barrier)
    float* red = (float*)lB;            // m[128] s[128] tg[128] av[128] + int[128]
    int* redi = (int*)(red + 512);
    if (l15 == 0) {
#pragma unroll
        for (int mf = 0; mf < 2; ++mf)
#pragma unroll
            for (int j = 0; j < 4; ++j) {
                int rowloc = wm * 32 + mf * 16 + l4 * 4 + j;
                int idx = wn * 64 + rowloc;
                red[idx]       = m_[mf][j];
                red[128 + idx] = s_[mf][j];
                red[256 + idx] = tg_[mf][j];
                red[384 + idx] = av_[mf][j];
                redi[idx]      = ai_[mf][j];
            }
    }
    __syncthreads();
    if (t < 64) {
        int grow = row0 + t;
        if (grow < nrows) {
            float M = red[t], S = red[128 + t], T = red[256 + t];
            float V = red[384 + t]; int I = redi[t];
            float m2 = red[64 + t], s2 = red[192 + t];
            float nm = fmaxf(M, m2);
            S = S * __expf(M - nm) + s2 * __expf(m2 - nm); M = nm;
            T += red[320 + t];
            float v2 = red[448 + t]; int i2 = redi[64 + t];
            if (v2 > V || (v2 == V && i2 < I)) { V = v2; I = i2; }
            int pidx = xm ? (grow * NSL + slice) : (BB * NSL + grow * NSL + slice);
            pm[pidx] = M; ps[pidx] = S; pt[pidx] = T; pv[pidx] = V; pi[pidx] = I;
        }
    }
}

// ---------------------------------------------------------------------------
// Merge partials per row -> CE / prec1 accumulators.
// ---------------------------------------------------------------------------
__global__ void merge_kernel(const float* __restrict__ pm, const float* __restrict__ ps,
                             const float* __restrict__ pt, const float* __restrict__ pv,
                             const int* __restrict__ pi, const int* __restrict__ label,
                             float* __restrict__ sums) {
    int tid = blockIdx.x * 256 + threadIdx.x;
    float ce = 0.f, corr = 0.f;
    int isx = (tid < BB) ? 1 : 0;
    int base = -1;
    if (tid < BB) base = tid * NSL;
    else if (tid < BB + NCC) base = BB * NSL + (tid - BB) * NSL;
    if (base >= 0) {
        float M = -1e30f, S = 0.f, T = 0.f, V = -1e30f; int I = 0x7fffffff;
#pragma unroll
        for (int s2 = 0; s2 < NSL; ++s2) {
            float m = pm[base + s2], s = ps[base + s2];
            float nm = fmaxf(M, m);
            S = S * __expf(M - nm) + s * __expf(m - nm); M = nm;
            T += pt[base + s2];
            float v = pv[base + s2]; int i2 = pi[base + s2];
            if (v > V || (v == V && i2 < I)) { V = v; I = i2; }
        }
        ce = -(T - M - logf(S));
        if (isx) corr = (I == label[tid]) ? 1.f : 0.f;
    }
#pragma unroll
    for (int off = 32; off; off >>= 1) {
        ce += __shfl_xor(ce, off);
        corr += __shfl_xor(corr, off);
    }
    if ((threadIdx.x & 63) == 0) {
        atomicAdd(&sums[isx ? 0 : 2], ce);
        if (isx) atomicAdd(&sums[1], corr);
    }
}

__global__ void finalize_kernel(const float* __restrict__ sums, float* __restrict__ out) {
    out[0] = sums[0] / (float)BB + sums[2] / (float)NCC;
    out[1] = 100.0f * sums[1] / (float)BB;
}

extern "C" void kernel_launch(void* const* d_in, const int* in_sizes, int n_in,
                              void* d_out, int out_size, void* d_ws, size_t ws_size,
                              hipStream_t stream) {
    const float* x       = (const float*)d_in[0];
    const int*   label   = (const int*)d_in[1];
    const float* centers = (const float*)d_in[2];
    const float* fc_w    = (const float*)d_in[3];
    const float* fc_b    = (const float*)d_in[4];
    const float* ch_w    = (const float*)d_in[5];
    const float* ch_b    = (const float*)d_in[6];
    float* out = (float*)d_out;

    // ws layout (float offsets):
    // 0: w[4096] | 4096: label_add[5994] | 10090: sums[6]
    // 14192: cadd[3068928]  (dead after newcenter; partials overlay it)
    //        14192: pm/ps/pt/pv/pi (5*121080 = 605400)
    // 3084144: xbuf bf16 x (1048576 slots = 524288 floats)
    // 4132720: ncbuf bf16 nc (3069952 bf16 slots)
    // 5667184: wbuf bf16 ch_w -> ends 6434416 floats (25.7 MB)
    float* ws = (float*)d_ws;
    float* w         = ws;
    float* label_add = ws + 4096;
    float* sums      = ws + 10090;
    float* cadd      = ws + 14192;
    float* pm        = ws + 14192;
    float* ps        = pm + PSZ;
    float* pt        = ps + PSZ;
    float* pv        = pt + PSZ;
    int*   pi        = (int*)(pv + PSZ);
    unsigned short* xbuf  = (unsigned short*)(ws + 3084144);
    unsigned short* ncbuf = (unsigned short*)(ws + 4132720);
    unsigned short* wbuf  = (unsigned short*)(ws + 5667184);

    hipMemsetAsync(label_add, 0, 6000 * sizeof(float), stream);   // label_add + sums

    prep_kernel<<<3307, 256, 0, stream>>>(label, w, label_add, x, ch_w, xbuf, wbuf, cadd);
    cadd_kernel<<<BB, 256, 0, stream>>>(x, label, w, cadd);
    newcenter_kernel<<<1499, 256, 0, stream>>>(centers, fc_w, fc_b, cadd, label_add, ncbuf);

    mfma_ce_kernel<<<NBLK, 256, 0, stream>>>(xbuf, ncbuf, wbuf, ch_b, label,
                                             pm, ps, pt, pv, pi);

    merge_kernel<<<(BB + NCC + 255) / 256, 256, 0, stream>>>(pm, ps, pt, pv, pi, label, sums);
    finalize_kernel<<<1, 1, 0, stream>>>(sums, out);
}